// Round 5
// baseline (491.065 us; speedup 1.0000x reference)
//
#include <hip/hip_runtime.h>

#define RES 64
#define R3  (RES*RES*RES)        // 262144
#define BB  8
#define CC  32
#define NN  65536
#define NBINS (BB*R3)            // 2097152
#define NPTS  (BB*NN)            // 524288
#define NORM_EPS 1e-8f

#define ALLOC_BINS 1024
#define NALLOC (NBINS/ALLOC_BINS)  // 2048 blocks, 256 per batch

// ws layout (byte offsets). total ~87.4 MB
//   header (4096B): [0] nm bits, [16..39] mins, [64..71] cursor[8]
#define OFF_COUNTS  4096
#define OFF_OFFSETS (OFF_COUNTS  + NBINS*4)
#define OFF_VOX     (OFF_OFFSETS + NBINS*4)
#define OFF_ORDER   (OFF_VOX     + NPTS*4)
#define OFF_FEATT   (OFF_ORDER   + NPTS*4)

__global__ __launch_bounds__(1024) void k_min(const float* __restrict__ pts, float* __restrict__ mins) {
    int ba = blockIdx.x;               // 0..23  => (b, axis)
    const float* p = pts + (size_t)ba * NN;
    float m = 1e30f;
    for (int i = threadIdx.x; i < NN; i += 1024) m = fminf(m, p[i]);
    __shared__ float red[1024];
    red[threadIdx.x] = m; __syncthreads();
    for (int s = 512; s > 0; s >>= 1) {
        if (threadIdx.x < s) red[threadIdx.x] = fminf(red[threadIdx.x], red[threadIdx.x + s]);
        __syncthreads();
    }
    if (threadIdx.x == 0) mins[ba] = red[0];
}

__global__ void k_normmax(const float* __restrict__ pts, const float* __restrict__ mins,
                          unsigned* __restrict__ nm) {
    int i = blockIdx.x * blockDim.x + threadIdx.x;   // over B*N
    int b = i >> 16, n = i & (NN - 1);
    const float* p = pts + (size_t)b * 3 * NN + n;
    float x = __fsub_rn(p[0],        mins[b*3+0]);
    float y = __fsub_rn(p[NN],       mins[b*3+1]);
    float z = __fsub_rn(p[2*NN],     mins[b*3+2]);
    float s = __fadd_rn(__fadd_rn(__fmul_rn(x, x), __fmul_rn(y, y)), __fmul_rn(z, z));
    float m = __fsqrt_rn(s);
    __shared__ float red[256];
    red[threadIdx.x] = m; __syncthreads();
    for (int st = 128; st > 0; st >>= 1) {
        if (threadIdx.x < st) red[threadIdx.x] = fmaxf(red[threadIdx.x], red[threadIdx.x + st]);
        __syncthreads();
    }
    if (threadIdx.x == 0) atomicMax(nm, __float_as_uint(red[0]));  // norms >= 0
}

// feat [B,C,N] -> featT [B,N,C], 32x32 tiles, float4 both sides
__global__ void k_transpose(const float* __restrict__ feat, float* __restrict__ featT) {
    __shared__ float tile[32][33];
    int blk = blockIdx.x;                  // b*(NN/32) + ntile
    int b  = blk >> 11;                    // NN/32 = 2048
    int n0 = (blk & 2047) << 5;
    int t = threadIdx.x;
    int c  = t >> 3;                       // 0..31
    int nq = t & 7;                        // float4 column
    float4 v = *(const float4*)(feat + ((size_t)b * CC + c) * NN + n0 + nq * 4);
    tile[c][nq*4+0] = v.x; tile[c][nq*4+1] = v.y;
    tile[c][nq*4+2] = v.z; tile[c][nq*4+3] = v.w;
    __syncthreads();
    int n  = t >> 3;                       // 0..31
    int cq = t & 7;
    float4 w = make_float4(tile[cq*4+0][n], tile[cq*4+1][n],
                           tile[cq*4+2][n], tile[cq*4+3][n]);
    *(float4*)(featT + ((size_t)b * NN + n0 + n) * CC + cq * 4) = w;
}

__global__ void k_voxid(const float* __restrict__ pts, const float* __restrict__ mins,
                        const unsigned* __restrict__ nm,
                        unsigned* __restrict__ voxid, unsigned* __restrict__ counts) {
    int i = blockIdx.x * blockDim.x + threadIdx.x;   // over B*N
    int b = i >> 16, n = i & (NN - 1);
    float denom = __fadd_rn(__uint_as_float(*nm), NORM_EPS);
    float inv = __fdiv_rn(1.0f, denom);              // XLA: divide -> mul by reciprocal
    const float* p = pts + (size_t)b * 3 * NN + n;
    float x = __fsub_rn(p[0],    mins[b*3+0]);
    float y = __fsub_rn(p[NN],   mins[b*3+1]);
    float z = __fsub_rn(p[2*NN], mins[b*3+2]);
    int ix = (int)(__fmul_rn(__fmul_rn(x, inv), 63.0f));
    int iy = (int)(__fmul_rn(__fmul_rn(y, inv), 63.0f));
    int iz = (int)(__fmul_rn(__fmul_rn(z, inv), 63.0f));
    ix = min(max(ix, 0), RES - 1);
    iy = min(max(iy, 0), RES - 1);
    iz = min(max(iz, 0), RES - 1);
    unsigned vox = (unsigned)(ix + iy * RES + iz * RES * RES);
    voxid[i] = vox;
    atomicAdd(&counts[(size_t)b * R3 + vox], 1u);
}

// Replaces 3-kernel scan: per-block LDS scan + one atomicAdd on a per-batch
// cursor. Bin ranges are contiguous per bin (all k_accum needs); inter-block
// order is non-deterministic, which only permutes fp-equal per-bin sums.
__global__ __launch_bounds__(256) void k_alloc(const unsigned* __restrict__ counts,
                                               unsigned* __restrict__ offsets,
                                               unsigned* __restrict__ cursor) {
    __shared__ unsigned red[256];
    __shared__ unsigned base;
    int blk = blockIdx.x, t = threadIdx.x;
    int b = blk >> 8;                                // 256 blocks per batch
    const unsigned* p = counts + (size_t)blk * ALLOC_BINS;
    unsigned v[4], s = 0;
    #pragma unroll
    for (int j = 0; j < 4; j++) { v[j] = p[t * 4 + j]; s += v[j]; }
    red[t] = s; __syncthreads();
    for (int st = 1; st < 256; st <<= 1) {
        unsigned tmp = (t >= st) ? red[t - st] : 0u;
        __syncthreads();
        red[t] += tmp;
        __syncthreads();
    }
    if (t == 255) base = atomicAdd(&cursor[b], red[255]);
    __syncthreads();
    unsigned acc = ((unsigned)b << 16) + base + red[t] - s;  // global exclusive start
    unsigned* q = offsets + (size_t)blk * ALLOC_BINS;
    #pragma unroll
    for (int j = 0; j < 4; j++) { q[t * 4 + j] = acc; acc += v[j]; }
}

__global__ void k_fill(const unsigned* __restrict__ voxid, unsigned* __restrict__ offsets,
                       unsigned* __restrict__ order) {
    int i = blockIdx.x * blockDim.x + threadIdx.x;   // over B*N
    int b = i >> 16;
    unsigned bin = ((unsigned)b << 18) + voxid[i];
    unsigned pos = atomicAdd(&offsets[bin], 1u);     // offsets becomes end-pointer
    order[pos] = (unsigned)i;
}

__global__ __launch_bounds__(256) void k_accum(
        const unsigned* __restrict__ counts, const unsigned* __restrict__ offsets,
        const unsigned* __restrict__ order, const float* __restrict__ featT,
        float* __restrict__ out) {
    __shared__ float tile[CC][260];                  // +4 pad
    int tid = threadIdx.x;
    int bin0 = blockIdx.x << 8;                      // 256 consecutive bins, same b
    int bin  = bin0 + tid;
    int b    = bin >> 18;                            // R3 = 2^18
    unsigned cnt   = counts[bin];
    unsigned end   = offsets[bin];                   // post-fill end pointer
    unsigned start = end - cnt;
    float acc[CC];
    #pragma unroll
    for (int c = 0; c < CC; c++) acc[c] = 0.f;
    for (unsigned k = start; k < end; k++) {
        unsigned i = order[k];
        const float4* ft = (const float4*)(featT + (size_t)i * CC);  // 128B aligned
        #pragma unroll
        for (int q = 0; q < CC / 4; q++) {
            float4 v = ft[q];
            acc[q*4+0] += v.x; acc[q*4+1] += v.y; acc[q*4+2] += v.z; acc[q*4+3] += v.w;
        }
    }
    float inv = __fdiv_rn(1.0f, fmaxf((float)cnt, 1.0f));
    #pragma unroll
    for (int c = 0; c < CC; c++) tile[c][tid] = __fmul_rn(acc[c], inv);
    __syncthreads();
    // transposed write: 1KB contiguous float4 rows per channel
    int vox0 = bin0 & (R3 - 1);
    float* ob = out + (size_t)b * CC * R3 + vox0;
    int lane64 = tid & 63;
    int crow   = tid >> 6;                            // 0..3
    #pragma unroll
    for (int cc = 0; cc < CC; cc += 4) {
        int c = cc + crow;
        float4 v = make_float4(tile[c][lane64*4+0], tile[c][lane64*4+1],
                               tile[c][lane64*4+2], tile[c][lane64*4+3]);
        *(float4*)(ob + (size_t)c * R3 + lane64*4) = v;
    }
}

extern "C" void kernel_launch(void* const* d_in, const int* in_sizes, int n_in,
                              void* d_out, int out_size, void* d_ws, size_t ws_size,
                              hipStream_t stream) {
    const float* pts  = (const float*)d_in[0];
    const float* feat = (const float*)d_in[1];
    float* out = (float*)d_out;

    char* ws = (char*)d_ws;
    unsigned* nm      = (unsigned*)ws;
    float*    mins    = (float*)ws + 16;
    unsigned* cursor  = (unsigned*)ws + 64;
    unsigned* counts  = (unsigned*)(ws + OFF_COUNTS);
    unsigned* offsets = (unsigned*)(ws + OFF_OFFSETS);
    unsigned* voxid   = (unsigned*)(ws + OFF_VOX);
    unsigned* order   = (unsigned*)(ws + OFF_ORDER);
    float*    featT   = (float*)(ws + OFF_FEATT);

    // zero header (nm, cursor) + counts in one shot
    hipMemsetAsync(d_ws, 0, OFF_COUNTS + (size_t)NBINS * 4, stream);

    k_min      <<<BB * 3,           1024, 0, stream>>>(pts, mins);
    k_normmax  <<<NPTS / 256,       256,  0, stream>>>(pts, mins, nm);
    k_transpose<<<BB * (NN / 32),   256,  0, stream>>>(feat, featT);
    k_voxid    <<<NPTS / 256,       256,  0, stream>>>(pts, mins, nm, voxid, counts);
    k_alloc    <<<NALLOC,           256,  0, stream>>>(counts, offsets, cursor);
    k_fill     <<<NPTS / 256,       256,  0, stream>>>(voxid, offsets, order);
    k_accum    <<<NBINS / 256,      256,  0, stream>>>(counts, offsets, order, featT, out);
}